// Round 4
// baseline (272.736 us; speedup 1.0000x reference)
//
#include <hip/hip_runtime.h>
#include <math.h>

#define NATOMS 4096
#define R_CUT 5.0f
#define JPT 4                 // j's per thread
#define BLOCK 256
#define JPB (BLOCK * JPT)     // 1024 j's per block tile
#define IPB 8                 // rows per block: j-tile register reuse factor

// clang-native 16B vector (HIP's float4 is a struct; the nontemporal
// builtin requires a real vector/scalar type).
typedef float fvec4 __attribute__((ext_vector_type(4)));

__global__ __launch_bounds__(BLOCK) void radius_graph_kernel(
    const float* __restrict__ pos,    // [N,3]
    const float* __restrict__ cell,   // [B,3,3]
    const int*   __restrict__ batch,  // [N]
    float* __restrict__ disp_out,     // [N,N,3]
    float* __restrict__ mask_out)     // [N,N] as 0/1 float
{
    __shared__ float sBuf[2 * JPB * 3];   // 24 KB, double-buffered disp staging

    const int bid = blockIdx.x;
    const int rg  = bid >> 2;        // row-group: 8 consecutive rows
    const int jc  = bid & 3;         // j-chunk: 4 chunks of 1024 j's
    const int tid = (int)threadIdx.x;

    const int j0 = jc * JPB + tid * JPT;

    // j-tile: loaded once per block, lives in registers for all IPB rows.
    const float4* pj = (const float4*)(pos + (size_t)j0 * 3);
    const float4 q0 = pj[0], q1 = pj[1], q2 = pj[2];
    const int4 bj4 = *(const int4*)(batch + j0);

    const float pjx[4] = { q0.x, q0.w, q1.z, q2.y };
    const float pjy[4] = { q0.y, q1.x, q1.w, q2.z };
    const float pjz[4] = { q0.z, q1.y, q2.x, q2.w };
    const int   bj[4]  = { bj4.x, bj4.y, bj4.z, bj4.w };

    const int i0 = rg * IPB;

    #pragma unroll 1
    for (int r = 0; r < IPB; ++r) {
        const int i = i0 + r;

        // Wave-uniform row data: scalar loads; redundant 3x3 inverse per thread.
        const int bi = batch[i];
        const float pix = pos[i * 3 + 0];
        const float piy = pos[i * 3 + 1];
        const float piz = pos[i * 3 + 2];

        const float* C = cell + (size_t)bi * 9;
        const float C00 = C[0], C01 = C[1], C02 = C[2];
        const float C10 = C[3], C11 = C[4], C12 = C[5];
        const float C20 = C[6], C21 = C[7], C22 = C[8];
        // A = inv(C^T) = cofactor(C) / det(C)
        const float cof00 =  (C11 * C22 - C12 * C21);
        const float cof01 = -(C10 * C22 - C12 * C20);
        const float cof02 =  (C10 * C21 - C11 * C20);
        const float cof10 = -(C01 * C22 - C02 * C21);
        const float cof11 =  (C00 * C22 - C02 * C20);
        const float cof12 = -(C00 * C21 - C01 * C20);
        const float cof20 =  (C01 * C12 - C02 * C11);
        const float cof21 = -(C00 * C12 - C02 * C10);
        const float cof22 =  (C00 * C11 - C01 * C10);
        const float det = C00 * cof00 + C01 * cof01 + C02 * cof02;
        const float id  = 1.0f / det;
        const float A00 = cof00 * id, A01 = cof01 * id, A02 = cof02 * id;
        const float A10 = cof10 * id, A11 = cof11 * id, A12 = cof12 * id;
        const float A20 = cof20 * id, A21 = cof21 * id, A22 = cof22 * id;

        float od[12];
        float om[4];

        #pragma unroll
        for (int t = 0; t < 4; ++t) {
            const int j = j0 + t;
            // raw displacement, exact-order f32 (matches numpy, no fma contraction)
            const float d0 = __fsub_rn(pix, pjx[t]);
            const float d1 = __fsub_rn(piy, pjy[t]);
            const float d2 = __fsub_rn(piz, pjz[t]);

            const float s0 = __fadd_rn(__fadd_rn(__fmul_rn(A00, d0), __fmul_rn(A01, d1)), __fmul_rn(A02, d2));
            const float s1 = __fadd_rn(__fadd_rn(__fmul_rn(A10, d0), __fmul_rn(A11, d1)), __fmul_rn(A12, d2));
            const float s2 = __fadd_rn(__fadd_rn(__fmul_rn(A20, d0), __fmul_rn(A21, d1)), __fmul_rn(A22, d2));

            const float r0 = rintf(s0);   // round-half-even == jnp.round
            const float r1 = rintf(s1);
            const float r2 = rintf(s2);

            const float w0 = __fsub_rn(d0, __fadd_rn(__fadd_rn(__fmul_rn(C00, r0), __fmul_rn(C01, r1)), __fmul_rn(C02, r2)));
            const float w1 = __fsub_rn(d1, __fadd_rn(__fadd_rn(__fmul_rn(C10, r0), __fmul_rn(C11, r1)), __fmul_rn(C12, r2)));
            const float w2 = __fsub_rn(d2, __fadd_rn(__fadd_rn(__fmul_rn(C20, r0), __fmul_rn(C21, r1)), __fmul_rn(C22, r2)));

            const float n2 = __fadd_rn(__fadd_rn(__fmul_rn(w0, w0), __fmul_rn(w1, w1)), __fmul_rn(w2, w2));
            const bool m = (bi == bj[t]) && (i != j) && (sqrtf(n2) < R_CUT);

            od[t * 3 + 0] = m ? w0 : 0.0f;
            od[t * 3 + 1] = m ? w1 : 0.0f;
            od[t * 3 + 2] = m ? w2 : 0.0f;
            om[t] = m ? 1.0f : 0.0f;
        }

        // Stage disp through LDS (double-buffered per row) so global stores are
        // lane-contiguous. Bank pattern (12*tid+4s) mod 32: conflict-free.
        fvec4* lb = (fvec4*)sBuf + (size_t)(r & 1) * (JPB * 3 / 4);
        lb[tid * 3 + 0] = (fvec4){od[0], od[1], od[2],  od[3]};
        lb[tid * 3 + 1] = (fvec4){od[4], od[5], od[6],  od[7]};
        lb[tid * 3 + 2] = (fvec4){od[8], od[9], od[10], od[11]};

        // mask store: coalesced 16 B/lane, NONTEMPORAL (no-allocate, stream to HBM)
        fvec4* mout = (fvec4*)(mask_out + (size_t)i * NATOMS + (size_t)jc * JPB);
        __builtin_nontemporal_store((fvec4){om[0], om[1], om[2], om[3]}, mout + tid);

        // LDS-only barrier: drain ds_writes + sync without draining vmcnt —
        // prior row's global stores stay in flight across the barrier.
        asm volatile("s_waitcnt lgkmcnt(0)\n\ts_barrier" ::: "memory");

        // Coalesced disp stores, NONTEMPORAL: bypass L2/L3 allocation — the
        // 268 MB output stream otherwise thrashes the 256 MB Infinity Cache
        // (allocate+evict vs streaming; the rocclr fill hits 6.6 TB/s with
        // streaming stores, we sit at 2.8 without).
        fvec4* gb = (fvec4*)(disp_out + (size_t)i * (NATOMS * 3) + (size_t)jc * (JPB * 3));
        __builtin_nontemporal_store(lb[0 * BLOCK + tid], gb + 0 * BLOCK + tid);
        __builtin_nontemporal_store(lb[1 * BLOCK + tid], gb + 1 * BLOCK + tid);
        __builtin_nontemporal_store(lb[2 * BLOCK + tid], gb + 2 * BLOCK + tid);
    }
}

extern "C" void kernel_launch(void* const* d_in, const int* in_sizes, int n_in,
                              void* d_out, int out_size, void* d_ws, size_t ws_size,
                              hipStream_t stream) {
    const float* pos   = (const float*)d_in[0];
    const float* cell  = (const float*)d_in[1];
    const int*   batch = (const int*)d_in[2];

    float* disp_out = (float*)d_out;
    float* mask_out = (float*)d_out + (size_t)NATOMS * NATOMS * 3;

    const int blocks = (NATOMS / IPB) * (NATOMS / JPB);  // 512 * 4 = 2048
    radius_graph_kernel<<<blocks, BLOCK, 0, stream>>>(pos, cell, batch, disp_out, mask_out);
}

// Round 5
// 262.675 us; speedup vs baseline: 1.0383x; 1.0383x over previous
//
#include <hip/hip_runtime.h>
#include <math.h>

#define NATOMS 4096
#define R_CUT 5.0f
#define BLOCK 256
#define GRID 2048
#define TPR (NATOMS / BLOCK)            // 16 tiles per row
#define NTILE (NATOMS * TPR)            // 65536 tiles; tile = (i, jb): 3KB disp + 1KB mask

// 12-byte vector store; force align 4 (addresses are 12B-strided).
typedef float f3 __attribute__((ext_vector_type(3), aligned(4)));

__global__ __launch_bounds__(BLOCK) void radius_graph_kernel(
    const float* __restrict__ pos,    // [N,3]
    const float* __restrict__ cell,   // [B,3,3]
    const int*   __restrict__ batch,  // [N]
    float* __restrict__ disp_out,     // [N,N,3]
    float* __restrict__ mask_out)     // [N,N] as 0/1 float
{
    const int tid = (int)threadIdx.x;

    // Persistent-grid linear tile sweep: the ~2048 co-resident blocks work on
    // CONSECUTIVE tiles at all times -> instantaneous write window is a
    // compact ~6 MB region sweeping disp_out front-to-back (plus a parallel
    // compact mask stream), instead of 2048 scattered 12KB windows. This
    // mimics the rocclr fill's address order (6.6 TB/s) to maximize DRAM
    // row-buffer hit rate; all prior variants scattered (2.8 TB/s effective).
    for (int T = (int)blockIdx.x; T < NTILE; T += GRID) {
        const int i  = T >> 4;          // row
        const int jb = T & (TPR - 1);   // j-chunk within row
        const int j  = jb * BLOCK + tid;

        // Wave-uniform row data: scalar loads + redundant 3x3 inverse (SALU-ish).
        const int bi = batch[i];
        const float pix = pos[i * 3 + 0];
        const float piy = pos[i * 3 + 1];
        const float piz = pos[i * 3 + 2];

        const float* C = cell + (size_t)bi * 9;
        const float C00 = C[0], C01 = C[1], C02 = C[2];
        const float C10 = C[3], C11 = C[4], C12 = C[5];
        const float C20 = C[6], C21 = C[7], C22 = C[8];
        // A = inv(C^T) = cofactor(C) / det(C)
        const float cof00 =  (C11 * C22 - C12 * C21);
        const float cof01 = -(C10 * C22 - C12 * C20);
        const float cof02 =  (C10 * C21 - C11 * C20);
        const float cof10 = -(C01 * C22 - C02 * C21);
        const float cof11 =  (C00 * C22 - C02 * C20);
        const float cof12 = -(C00 * C21 - C01 * C20);
        const float cof20 =  (C01 * C12 - C02 * C11);
        const float cof21 = -(C00 * C12 - C02 * C10);
        const float cof22 =  (C00 * C11 - C01 * C10);
        const float det = C00 * cof00 + C01 * cof01 + C02 * cof02;
        const float id  = 1.0f / det;
        const float A00 = cof00 * id, A01 = cof01 * id, A02 = cof02 * id;
        const float A10 = cof10 * id, A11 = cof11 * id, A12 = cof12 * id;
        const float A20 = cof20 * id, A21 = cof21 * id, A22 = cof22 * id;

        // Per-thread j data: coalesced-ish loads, pos/batch are L1/L2 resident.
        const float pjx = pos[j * 3 + 0];
        const float pjy = pos[j * 3 + 1];
        const float pjz = pos[j * 3 + 2];
        const int   bjv = batch[j];

        // raw displacement, exact-order f32 (matches numpy, no fma contraction)
        const float d0 = __fsub_rn(pix, pjx);
        const float d1 = __fsub_rn(piy, pjy);
        const float d2 = __fsub_rn(piz, pjz);

        // scaled = inv(cell^T) @ d
        const float s0 = __fadd_rn(__fadd_rn(__fmul_rn(A00, d0), __fmul_rn(A01, d1)), __fmul_rn(A02, d2));
        const float s1 = __fadd_rn(__fadd_rn(__fmul_rn(A10, d0), __fmul_rn(A11, d1)), __fmul_rn(A12, d2));
        const float s2 = __fadd_rn(__fadd_rn(__fmul_rn(A20, d0), __fmul_rn(A21, d1)), __fmul_rn(A22, d2));

        const float r0 = rintf(s0);   // round-half-even == jnp.round
        const float r1 = rintf(s1);
        const float r2 = rintf(s2);

        // wrapped = d - cell @ r, exact numpy order, no contraction
        const float w0 = __fsub_rn(d0, __fadd_rn(__fadd_rn(__fmul_rn(C00, r0), __fmul_rn(C01, r1)), __fmul_rn(C02, r2)));
        const float w1 = __fsub_rn(d1, __fadd_rn(__fadd_rn(__fmul_rn(C10, r0), __fmul_rn(C11, r1)), __fmul_rn(C12, r2)));
        const float w2 = __fsub_rn(d2, __fadd_rn(__fadd_rn(__fmul_rn(C20, r0), __fmul_rn(C21, r1)), __fmul_rn(C22, r2)));

        const float n2 = __fadd_rn(__fadd_rn(__fmul_rn(w0, w0), __fmul_rn(w1, w1)), __fmul_rn(w2, w2));
        const bool m = (bi == bjv) && (i != j) && (sqrtf(n2) < R_CUT);

        // Stores: disp tile is 3KB contiguous (wave: 768B = 12 full 64B lines),
        // mask tile 1KB contiguous (wave: 256B = 4 full lines). Plain stores —
        // the fill proves plain stores reach 6.6 TB/s with this ordering.
        f3 v;
        v.x = m ? w0 : 0.0f;
        v.y = m ? w1 : 0.0f;
        v.z = m ? w2 : 0.0f;
        *(f3*)(disp_out + (size_t)T * (BLOCK * 3) + (size_t)tid * 3) = v;
        mask_out[(size_t)T * BLOCK + tid] = m ? 1.0f : 0.0f;
    }
}

extern "C" void kernel_launch(void* const* d_in, const int* in_sizes, int n_in,
                              void* d_out, int out_size, void* d_ws, size_t ws_size,
                              hipStream_t stream) {
    const float* pos   = (const float*)d_in[0];
    const float* cell  = (const float*)d_in[1];
    const int*   batch = (const int*)d_in[2];

    float* disp_out = (float*)d_out;
    float* mask_out = (float*)d_out + (size_t)NATOMS * NATOMS * 3;

    radius_graph_kernel<<<GRID, BLOCK, 0, stream>>>(pos, cell, batch, disp_out, mask_out);
}